// Round 3
// baseline (4768.734 us; speedup 1.0000x reference)
//
#include <hip/hip_runtime.h>
#include <hip/hip_cooperative_groups.h>
#include <hip/hip_bf16.h>
#include <math.h>

namespace cg = cooperative_groups;

#define Bsz 64
#define Pp  196
#define ENC 2048
#define Ee  512
#define Hh  512
#define Vv  10000
#define Tt  20
#define H4  2048

__device__ __forceinline__ float sigmoidf_(float x) { return 1.0f / (1.0f + expf(-x)); }

// ---------------- v_enc[e] = sum_a W_full[a] * W_enc[a][e] ----------------
__global__ __launch_bounds__(256) void k_venc(const float* __restrict__ W_full,
                                              const float* __restrict__ W_enc,
                                              float* __restrict__ v_enc) {
    int lane = threadIdx.x & 63, ag = threadIdx.x >> 6;
    int e = blockIdx.x * 64 + lane;
    float s = 0.f;
    #pragma unroll 8
    for (int a = ag * 128; a < ag * 128 + 128; ++a)
        s += W_full[a] * W_enc[(size_t)a * ENC + e];
    __shared__ float red[4][64];
    red[ag][lane] = s;
    __syncthreads();
    if (threadIdx.x < 64)
        v_enc[e] = red[0][lane] + red[1][lane] + red[2][lane] + red[3][lane];
}

// ---------------- scores: sc[b][p] = dot(img[b][p], v_enc) ----------------
__global__ __launch_bounds__(256) void k_scores(const float* __restrict__ img,
                                                const float* __restrict__ v_enc,
                                                float* __restrict__ sc) {
    int b = blockIdx.y;
    int wave = threadIdx.x >> 6, lane = threadIdx.x & 63;
    int p = blockIdx.x * 4 + wave;
    __shared__ float4 sv[ENC / 4];
    const float4* ve4 = (const float4*)v_enc;
    sv[threadIdx.x] = ve4[threadIdx.x];
    sv[threadIdx.x + 256] = ve4[threadIdx.x + 256];
    __syncthreads();
    const float4* row = (const float4*)(img + ((size_t)b * Pp + p) * ENC);
    float s = 0.f;
    #pragma unroll
    for (int it = 0; it < 8; ++it) {
        int idx = it * 64 + lane;
        float4 v = row[idx];
        float4 w = sv[idx];
        s += v.x * w.x + v.y * w.y + v.z * w.z + v.w * w.w;
    }
    #pragma unroll
    for (int off = 32; off > 0; off >>= 1) s += __shfl_down(s, off);
    if (lane == 0) sc[b * Pp + p] = s;
}

// ---------------- softmax + alphas broadcast ----------------
__global__ __launch_bounds__(256) void k_softmax(const float* __restrict__ sc,
                                                 float* __restrict__ alpha,
                                                 float* __restrict__ alphas_out) {
    int b = blockIdx.x, tid = threadIdx.x;
    __shared__ float red[256];
    __shared__ float sa[Pp];
    float v = (tid < Pp) ? sc[b * Pp + tid] : -INFINITY;
    red[tid] = v; __syncthreads();
    for (int off = 128; off > 0; off >>= 1) {
        if (tid < off) red[tid] = fmaxf(red[tid], red[tid + off]);
        __syncthreads();
    }
    float mx = red[0]; __syncthreads();
    float ex = (tid < Pp) ? expf(v - mx) : 0.f;
    red[tid] = ex; __syncthreads();
    for (int off = 128; off > 0; off >>= 1) {
        if (tid < off) red[tid] += red[tid + off];
        __syncthreads();
    }
    float inv = 1.f / red[0];
    if (tid < Pp) { sa[tid] = ex * inv; alpha[b * Pp + tid] = ex * inv; }
    __syncthreads();
    for (int i = tid; i < Tt * Pp; i += 256)
        alphas_out[(size_t)b * Tt * Pp + i] = sa[i % Pp];
}

// ---------------- context + avg ----------------
__global__ __launch_bounds__(256) void k_ctx(const float* __restrict__ img,
                                             const float* __restrict__ alpha,
                                             float* __restrict__ context,
                                             float* __restrict__ avg) {
    int b = blockIdx.y;
    int e2 = blockIdx.x * 256 + threadIdx.x;
    __shared__ float sa[Pp];
    if (threadIdx.x < Pp) sa[threadIdx.x] = alpha[b * Pp + threadIdx.x];
    __syncthreads();
    const float2* ib2 = (const float2*)(img + (size_t)b * Pp * ENC);
    float cx = 0.f, cy = 0.f, ax = 0.f, ay = 0.f;
    for (int p = 0; p < Pp; p += 4) {
        #pragma unroll
        for (int q = 0; q < 4; ++q) {
            float ap = sa[p + q];
            float2 v = ib2[(size_t)(p + q) * (ENC / 2) + e2];
            cx += ap * v.x; cy += ap * v.y;
            ax += v.x;      ay += v.y;
        }
    }
    float2* c2 = (float2*)(context + (size_t)b * ENC);
    float2* a2 = (float2*)(avg + (size_t)b * ENC);
    c2[e2] = make_float2(cx, cy);
    a2[e2] = make_float2(ax * (1.f / 196.f), ay * (1.f / 196.f));
}

// ---------------- embedding gather ----------------
__global__ __launch_bounds__(256) void k_gather(const int* __restrict__ captions,
                                                const float* __restrict__ emb,
                                                float* __restrict__ emb_all) {
    int i4 = blockIdx.x * 256 + threadIdx.x;
    if (i4 >= Tt * Bsz * (Ee / 4)) return;
    int row = i4 >> 7, e4 = i4 & 127;
    int t = row / Bsz, b = row % Bsz;
    int cap = captions[b * Tt + t];
    float4 val = ((const float4*)(emb + (size_t)cap * Ee))[e4];
    ((float4*)(emb_all + (size_t)row * Ee))[e4] = val;
}

// ---------------- init: hc[64][1024] = avg @ [Wh|Wc]^T + [bh|bc] ----------------
__global__ __launch_bounds__(256) void k_init(const float* __restrict__ avg,
                                              const float* __restrict__ Wh, const float* __restrict__ bh,
                                              const float* __restrict__ Wc, const float* __restrict__ bc,
                                              float* __restrict__ hc) {
    const int tid = threadIdx.x;
    const int tx = tid & 15, ty = tid >> 4;
    const int n0 = blockIdx.x * 16;
    const float* Bm = (n0 < 512) ? Wh : Wc;
    const float* bias = (n0 < 512) ? bh : bc;
    int nn0 = (n0 < 512) ? n0 : n0 - 512;

    __shared__ float As[64][68];
    __shared__ float Bs[64][20];

    float4 pa[4]; float4 pb;
    const int sm[4] = { (0*256+tid) >> 4, (1*256+tid) >> 4, (2*256+tid) >> 4, (3*256+tid) >> 4 };
    const int scc = tid & 15;
    const int bn = tid >> 4, bc_ = tid & 15;

    float acc[4] = {};
    for (int c = 0; c < 32; ++c) {
        int k0 = c * 64;
        #pragma unroll
        for (int i = 0; i < 4; ++i)
            pa[i] = *(const float4*)(avg + (size_t)sm[i] * ENC + k0 + 4 * scc);
        pb = *(const float4*)(Bm + (size_t)(nn0 + bn) * ENC + k0 + 4 * bc_);
        __syncthreads();
        #pragma unroll
        for (int i = 0; i < 4; ++i) {
            As[4*scc+0][sm[i]] = pa[i].x; As[4*scc+1][sm[i]] = pa[i].y;
            As[4*scc+2][sm[i]] = pa[i].z; As[4*scc+3][sm[i]] = pa[i].w;
        }
        Bs[4*bc_+0][bn] = pb.x; Bs[4*bc_+1][bn] = pb.y;
        Bs[4*bc_+2][bn] = pb.z; Bs[4*bc_+3][bn] = pb.w;
        __syncthreads();
        #pragma unroll 8
        for (int kk = 0; kk < 64; ++kk) {
            float4 a = *(const float4*)&As[kk][ty * 4];
            float bb = Bs[kk][tx];
            acc[0] += a.x * bb; acc[1] += a.y * bb;
            acc[2] += a.z * bb; acc[3] += a.w * bb;
        }
    }
    int gn = n0 + tx;
    #pragma unroll
    for (int i = 0; i < 4; ++i)
        hc[(size_t)(ty * 4 + i) * 1024 + gn] = acc[i] + bias[(n0 < 512) ? gn : gn - 512];
}

// ---------------- big GEMM: BM=128, BN=64, BK=32, TM=8, TN=4 ----------------
template<int MODE>
__global__ __launch_bounds__(256) void gemm_big(const float* __restrict__ A, int lda,
                                                const float* __restrict__ Bm, int ldb,
                                                float* __restrict__ C, int ldc,
                                                int N, int K,
                                                const float* __restrict__ bias,
                                                const float* __restrict__ bias2) {
    const int tid = threadIdx.x;
    const int tx = tid & 15, ty = tid >> 4;
    const int m0 = blockIdx.y * 128, n0 = blockIdx.x * 64;

    __shared__ float As[32][132];
    __shared__ float Bs[32][68];

    float4 pa[4]; float4 pb[2];
    const int am[4] = { (0*256+tid) >> 3, (1*256+tid) >> 3, (2*256+tid) >> 3, (3*256+tid) >> 3 };
    const int ac = tid & 7;
    const int bnr[2] = { (0*256+tid) >> 3, (1*256+tid) >> 3 };
    const int bc = tid & 7;

    const int nchunk = K / 32;
    auto load_chunk = [&](int c) {
        int k0 = c * 32;
        #pragma unroll
        for (int i = 0; i < 4; ++i)
            pa[i] = *(const float4*)(A + (size_t)(m0 + am[i]) * lda + k0 + 4 * ac);
        #pragma unroll
        for (int i = 0; i < 2; ++i) {
            int gn = n0 + bnr[i];
            if (MODE == 1 && gn >= N) pb[i] = make_float4(0.f, 0.f, 0.f, 0.f);
            else pb[i] = *(const float4*)(Bm + (size_t)gn * ldb + k0 + 4 * bc);
        }
    };

    float acc[8][4] = {};
    load_chunk(0);
    for (int c = 0; c < nchunk; ++c) {
        __syncthreads();
        #pragma unroll
        for (int i = 0; i < 4; ++i) {
            As[4*ac+0][am[i]] = pa[i].x; As[4*ac+1][am[i]] = pa[i].y;
            As[4*ac+2][am[i]] = pa[i].z; As[4*ac+3][am[i]] = pa[i].w;
        }
        #pragma unroll
        for (int i = 0; i < 2; ++i) {
            Bs[4*bc+0][bnr[i]] = pb[i].x; Bs[4*bc+1][bnr[i]] = pb[i].y;
            Bs[4*bc+2][bnr[i]] = pb[i].z; Bs[4*bc+3][bnr[i]] = pb[i].w;
        }
        __syncthreads();
        if (c + 1 < nchunk) load_chunk(c + 1);
        #pragma unroll 4
        for (int kk = 0; kk < 32; ++kk) {
            float4 a0 = *(const float4*)&As[kk][ty * 8];
            float4 a1 = *(const float4*)&As[kk][ty * 8 + 4];
            float4 b0 = *(const float4*)&Bs[kk][tx * 4];
            float av[8] = { a0.x, a0.y, a0.z, a0.w, a1.x, a1.y, a1.z, a1.w };
            float bv[4] = { b0.x, b0.y, b0.z, b0.w };
            #pragma unroll
            for (int i = 0; i < 8; ++i)
                #pragma unroll
                for (int j = 0; j < 4; ++j)
                    acc[i][j] += av[i] * bv[j];
        }
    }

    #pragma unroll
    for (int i = 0; i < 8; ++i) {
        int m = m0 + ty * 8 + i;
        #pragma unroll
        for (int j = 0; j < 4; ++j) {
            int gn = n0 + tx * 4 + j;
            if (MODE == 1 && gn >= N) continue;
            float v = acc[i][j] + bias[gn];
            if (MODE == 0) {
                v += bias2[gn];
                C[(size_t)m * ldc + gn] = v;
            } else {
                int t = m >> 6, b = m & 63;
                C[(size_t)(b * Tt + t) * ldc + gn] = v;
            }
        }
    }
}

// ---------------- persistent cooperative recurrent loop ----------------
// 256 blocks x 256 threads. Block bid owns:
//   phase A: gc cols [bid*8, bid*8+8)
//   phase B: j-pair j0=bid*2 with all 4 gates -> fused LSTM, c-state in LDS.
// Thread coords: cq=tid&1 (c-quad), bq=(tid>>1)&15 (b-quad), kq=tid>>5 (k-slice of 8).
__global__ __launch_bounds__(256) void k_loop(
    const float* __restrict__ hc,        // [64][1024] initial h|c
    float* __restrict__ hPing,           // [64][512]
    float* __restrict__ hPong,           // [64][512]
    float* __restrict__ gc,              // [64][2048]
    const float* __restrict__ context,   // [64][2048]
    const float* __restrict__ emb_part,  // [T*64][2048] gates prefill
    const float* __restrict__ W_beta,    // [2048][512]
    const float* __restrict__ b_beta,
    const float* __restrict__ W_ih,      // [2048][2560]
    const float* __restrict__ W_hh,      // [2048][512]
    float* __restrict__ H_all)           // [T*64][512]
{
    cg::grid_group grid = cg::this_grid();
    const int bid = blockIdx.x;
    const int tid = threadIdx.x;

    const int cq = tid & 1;
    const int bq = (tid >> 1) & 15;
    const int kq = tid >> 5;

    const int ca0 = bid * 8;
    const int j0  = bid * 2;

    __shared__ float4 As[2][64][17];
    __shared__ float4 Ws[2][8][17];
    __shared__ float  ctxS[64][8];
    __shared__ float  csS[64][2];
    __shared__ float  redf[4096];
    __shared__ float  gbuf[8 * 64];

    for (int i = tid; i < 512; i += 256) {
        int b = i >> 3, c = i & 7;
        ctxS[b][c] = context[(size_t)b * 2048 + ca0 + c];
    }
    if (tid < 128) {
        int b = tid >> 1, jj = tid & 1;
        csS[b][jj] = hc[(size_t)b * 1024 + 512 + j0 + jj];
    }
    __syncthreads();

    float4 pa[4]; float4 pw;
    float acc[4][4];

    for (int t = 0; t < Tt; ++t) {
        const float* hcur; int hlda;
        if (t == 0)      { hcur = hc;    hlda = 1024; }
        else if (t & 1)  { hcur = hPing; hlda = 512;  }
        else             { hcur = hPong; hlda = 512;  }
        float* hnext = (t & 1) ? hPong : hPing;

        for (int phase = 0; phase < 2; ++phase) {
            const int nch = (phase == 0) ? 8 : 40;

            auto srcA = [&](int ch, int m) -> const float* {
                int k0 = ch * 64;
                if (phase == 0) return hcur + (size_t)m * hlda + k0;
                if (ch < 32)    return gc + (size_t)m * 2048 + k0;
                return hcur + (size_t)m * hlda + (k0 - 2048);
            };
            auto srcW = [&](int ch, int r) -> const float* {
                int k0 = ch * 64;
                if (phase == 0) return W_beta + (size_t)(ca0 + r) * 512 + k0;
                int rowr = (r >> 1) * 512 + j0 + (r & 1);
                if (ch < 32) return W_ih + (size_t)rowr * 2560 + 512 + k0;
                return W_hh + (size_t)rowr * 512 + (k0 - 2048);
            };
            auto load_regs = [&](int ch) {
                #pragma unroll
                for (int i = 0; i < 4; ++i) {
                    int idx = i * 256 + tid;
                    int m = idx >> 4, k4l = idx & 15;
                    pa[i] = *(const float4*)(srcA(ch, m) + 4 * k4l);
                }
                if (tid < 128) {
                    int r = tid >> 4, k4l = tid & 15;
                    pw = *(const float4*)(srcW(ch, r) + 4 * k4l);
                }
            };
            auto store_lds = [&](int p) {
                #pragma unroll
                for (int i = 0; i < 4; ++i) {
                    int idx = i * 256 + tid;
                    int m = idx >> 4, k4l = idx & 15;
                    As[p][m][k4l ^ ((m >> 2) & 15)] = pa[i];
                }
                if (tid < 128) {
                    int r = tid >> 4, k4l = tid & 15;
                    Ws[p][r][k4l] = pw;
                }
            };

            #pragma unroll
            for (int i = 0; i < 4; ++i)
                #pragma unroll
                for (int j = 0; j < 4; ++j) acc[i][j] = 0.f;

            load_regs(0);
            store_lds(0);
            __syncthreads();
            for (int ch = 0; ch < nch; ++ch) {
                if (ch + 1 < nch) load_regs(ch + 1);
                int p = ch & 1;
                #pragma unroll
                for (int k2 = 0; k2 < 2; ++k2) {
                    int k4 = kq * 2 + k2;
                    float4 a[4], w[4];
                    #pragma unroll
                    for (int i = 0; i < 4; ++i) {
                        int b = bq * 4 + i;
                        a[i] = As[p][b][k4 ^ bq];
                    }
                    #pragma unroll
                    for (int j = 0; j < 4; ++j)
                        w[j] = Ws[p][cq * 4 + j][k4];
                    #pragma unroll
                    for (int i = 0; i < 4; ++i)
                        #pragma unroll
                        for (int j = 0; j < 4; ++j)
                            acc[i][j] += a[i].x * w[j].x + a[i].y * w[j].y
                                       + a[i].z * w[j].z + a[i].w * w[j].w;
                }
                __syncthreads();
                if (ch + 1 < nch) { store_lds((ch + 1) & 1); __syncthreads(); }
            }

            // K-slice reduction through LDS
            int slot = (kq * 16 + bq) * 2 + cq;
            #pragma unroll
            for (int i = 0; i < 4; ++i)
                *(float4*)&redf[(slot * 4 + i) * 4] =
                    make_float4(acc[i][0], acc[i][1], acc[i][2], acc[i][3]);
            __syncthreads();

            if (phase == 0) {
                #pragma unroll
                for (int oo = 0; oo < 2; ++oo) {
                    int o = oo * 256 + tid;
                    int b = o >> 3, c = o & 7;
                    float v = 0.f;
                    #pragma unroll
                    for (int k2 = 0; k2 < 8; ++k2)
                        v += redf[(((k2 * 16 + (b >> 2)) * 2 + (c >> 2)) * 4 + (b & 3)) * 4 + (c & 3)];
                    float gcv = sigmoidf_(v + b_beta[ca0 + c]) * ctxS[b][c];
                    gc[(size_t)b * 2048 + ca0 + c] = gcv;
                }
                __threadfence();
                grid.sync();
            } else {
                #pragma unroll
                for (int oo = 0; oo < 2; ++oo) {
                    int o = oo * 256 + tid;
                    int b = o >> 3, c = o & 7;
                    float v = 0.f;
                    #pragma unroll
                    for (int k2 = 0; k2 < 8; ++k2)
                        v += redf[(((k2 * 16 + (b >> 2)) * 2 + (c >> 2)) * 4 + (b & 3)) * 4 + (c & 3)];
                    int rowr = (c >> 1) * 512 + j0 + (c & 1);
                    gbuf[c * 64 + b] = v + emb_part[((size_t)t * 64 + b) * 2048 + rowr];
                }
                __syncthreads();
                if (tid < 128) {
                    int b = tid >> 1, jj = tid & 1;
                    float ig = sigmoidf_(gbuf[(0 * 2 + jj) * 64 + b]);
                    float fg = sigmoidf_(gbuf[(1 * 2 + jj) * 64 + b]);
                    float gg = tanhf(gbuf[(2 * 2 + jj) * 64 + b]);
                    float og = sigmoidf_(gbuf[(3 * 2 + jj) * 64 + b]);
                    float cn = fg * csS[b][jj] + ig * gg;
                    float hn = og * tanhf(cn);
                    csS[b][jj] = cn;
                    hnext[(size_t)b * 512 + j0 + jj] = hn;
                    H_all[((size_t)t * 64 + b) * 512 + j0 + jj] = hn;
                }
                __threadfence();
                grid.sync();
            }
        }
    }
}

extern "C" void kernel_launch(void* const* d_in, const int* in_sizes, int n_in,
                              void* d_out, int out_size, void* d_ws, size_t ws_size,
                              hipStream_t stream) {
    const float* img_feat  = (const float*)d_in[0];
    const int*   captions  = (const int*)d_in[1];
    const float* embedding = (const float*)d_in[2];
    const float* W_enc_att = (const float*)d_in[3];
    const float* W_full    = (const float*)d_in[7];
    const float* W_beta    = (const float*)d_in[9];
    const float* b_beta    = (const float*)d_in[10];
    const float* W_ih      = (const float*)d_in[11];
    const float* b_ih      = (const float*)d_in[12];
    const float* W_hh      = (const float*)d_in[13];
    const float* b_hh      = (const float*)d_in[14];
    const float* W_init_h  = (const float*)d_in[15];
    const float* b_init_h  = (const float*)d_in[16];
    const float* W_init_c  = (const float*)d_in[17];
    const float* b_init_c  = (const float*)d_in[18];
    const float* W_out     = (const float*)d_in[19];
    const float* b_out     = (const float*)d_in[20];

    float* preds_out  = (float*)d_out;
    float* alphas_out = (float*)d_out + (size_t)Bsz * Tt * Vv;

    float* ws = (float*)d_ws;
    float* v_enc    = ws;                        // 2048
    float* sc       = v_enc + ENC;               // 64*196
    float* alpha    = sc + Bsz * Pp;             // 64*196
    float* context  = alpha + Bsz * Pp;          // 64*2048
    float* avg      = context + Bsz * ENC;       // 64*2048
    float* hc       = avg + Bsz * ENC;           // 64*1024
    float* hPing    = hc + Bsz * 1024;           // 64*512
    float* hPong    = hPing + Bsz * Hh;          // 64*512
    float* gcbuf    = hPong + Bsz * Hh;          // 64*2048
    float* emb_all  = gcbuf + Bsz * ENC;         // 1280*512
    float* emb_part = emb_all + Tt * Bsz * Ee;   // 1280*2048
    float* H_all    = emb_part + (size_t)Tt * Bsz * H4; // 1280*512

    // attention (timestep-invariant)
    k_venc<<<32, 256, 0, stream>>>(W_full, W_enc_att, v_enc);
    k_scores<<<dim3(49, 64), 256, 0, stream>>>(img_feat, v_enc, sc);
    k_softmax<<<64, 256, 0, stream>>>(sc, alpha, alphas_out);
    k_ctx<<<dim3(4, 64), 256, 0, stream>>>(img_feat, alpha, context, avg);

    // init h|c
    k_init<<<64, 256, 0, stream>>>(avg, W_init_h, b_init_h, W_init_c, b_init_c, hc);

    // embedding part of gates for all steps (includes b_ih + b_hh)
    k_gather<<<(Tt * Bsz * (Ee / 4) + 255) / 256, 256, 0, stream>>>(captions, embedding, emb_all);
    gemm_big<0><<<dim3(H4 / 64, (Tt * Bsz) / 128), 256, 0, stream>>>(
        emb_all, Ee, W_ih, Ee + ENC, emb_part, H4, H4, Ee, b_ih, b_hh);

    // persistent recurrent loop (cooperative)
    {
        void* args[] = { (void*)&hc, (void*)&hPing, (void*)&hPong, (void*)&gcbuf,
                         (void*)&context, (void*)&emb_part, (void*)&W_beta, (void*)&b_beta,
                         (void*)&W_ih, (void*)&W_hh, (void*)&H_all };
        hipLaunchCooperativeKernel((void*)k_loop, dim3(256), dim3(256), args, 0, stream);
    }

    // preds = H_all @ W_out^T + b_out (row remap)
    gemm_big<1><<<dim3((Vv + 63) / 64, (Tt * Bsz) / 128), 256, 0, stream>>>(
        H_all, Hh, W_out, Hh, preds_out, Vv, Vv, Hh, b_out, nullptr);
}